// Round 2
// baseline (241.893 us; speedup 1.0000x reference)
//
#include <hip/hip_runtime.h>

typedef __attribute__((ext_vector_type(8))) short short8;
typedef __attribute__((ext_vector_type(8))) unsigned short u16x8;
typedef __attribute__((ext_vector_type(4))) float f32x4;

__device__ inline unsigned short f2bf(float f) {
  union { float f; unsigned int u; } v; v.f = f;
  unsigned int r = v.u + 0x7FFFu + ((v.u >> 16) & 1u);
  return (unsigned short)(r >> 16);
}

__device__ inline void gload_lds16(const void* g, void* l) {
  __builtin_amdgcn_global_load_lds(
      (const __attribute__((address_space(1))) unsigned int*)g,
      (__attribute__((address_space(3))) unsigned int*)l, 16, 0, 0);
}

// ---------------- conversion kernels ----------------

__global__ void cvt_bf16(const float4* __restrict__ in, ushort4* __restrict__ out) {
  const int i = blockIdx.x * blockDim.x + threadIdx.x;
  float4 v = in[i];
  ushort4 o;
  o.x = f2bf(v.x); o.y = f2bf(v.y); o.z = f2bf(v.z); o.w = f2bf(v.w);
  out[i] = o;
}

// wT[n][k] = w[k][n] * scale   (w is [1024][1024] fp32 row-major)
__global__ __launch_bounds__(256) void cvt_wT(const float* __restrict__ w,
                                              unsigned short* __restrict__ wT,
                                              float scale) {
  __shared__ float t[32][33];
  const int k0 = blockIdx.x * 32;
  const int n0 = blockIdx.y * 32;
  const int tx = threadIdx.x & 31, ty = threadIdx.x >> 5;  // 32 x 8
#pragma unroll
  for (int i = 0; i < 32; i += 8)
    t[ty + i][tx] = w[(size_t)(k0 + ty + i) * 1024 + n0 + tx];
  __syncthreads();
#pragma unroll
  for (int i = 0; i < 32; i += 8)
    wT[(size_t)(n0 + ty + i) * 1024 + k0 + tx] = f2bf(t[tx][ty + i] * scale);
}

__global__ void pack_bias(const float* __restrict__ bq, const float* __restrict__ bk,
                          const float* __restrict__ bv, float* __restrict__ out) {
  const int i = blockIdx.x * 256 + threadIdx.x;  // 0..3071
  float v;
  if (i < 1024) v = bq[i] * 0.125f;
  else if (i < 2048) v = bk[i - 1024];
  else v = bv[i - 2048];
  out[i] = v;
}

// ---------------- GEMM: C[M,·] = A[M,K] @ Bt[N,K]^T + bias ----------------
// m97 structure: 128x128 tile, BK=32, 4 waves (2x2 of 64x64), global_load_lds staging.
// OutT = unsigned short (bf16) or float (fp32).

template <typename OutT>
__global__ __launch_bounds__(256) void gemm_bt(
    const unsigned short* __restrict__ A, const unsigned short* __restrict__ Bt,
    const float* __restrict__ bias, OutT* __restrict__ C,
    int K, int ldc) {
  __shared__ unsigned short As[128 * 32];
  __shared__ unsigned short Bs[128 * 32];
  const int tid = threadIdx.x;
  const int lane = tid & 63;
  const int wave = tid >> 6;
  const int wm = (wave >> 1) * 64;
  const int wn = (wave & 1) * 64;
  const long bm = (long)blockIdx.x * 128;
  const long bn = (long)blockIdx.y * 128;

  const int sr = tid >> 2;        // staging row 0..63
  const int sc = (tid & 3) * 8;   // staging col (elements)
  const unsigned short* Ag0 = A + (bm + sr) * (long)K + sc;
  const unsigned short* Ag1 = A + (bm + 64 + sr) * (long)K + sc;
  const unsigned short* Bg0 = Bt + (bn + sr) * (long)K + sc;
  const unsigned short* Bg1 = Bt + (bn + 64 + sr) * (long)K + sc;
  unsigned short* As0 = &As[tid * 8];
  unsigned short* As1 = &As[2048 + tid * 8];
  unsigned short* Bs0 = &Bs[tid * 8];
  unsigned short* Bs1 = &Bs[2048 + tid * 8];

  f32x4 acc[4][4] = {};

  const int fr = lane & 15;       // fragment row (M) / col (N)
  const int fk = (lane >> 4) * 8; // fragment k offset

  for (int kt = 0; kt < K; kt += 32) {
    gload_lds16(Ag0, As0);
    gload_lds16(Ag1, As1);
    gload_lds16(Bg0, Bs0);
    gload_lds16(Bg1, Bs1);
    Ag0 += 32; Ag1 += 32; Bg0 += 32; Bg1 += 32;
    __syncthreads();
    short8 af[4], bfv[4];
#pragma unroll
    for (int i = 0; i < 4; i++) af[i] = *(const short8*)&As[(wm + i * 16 + fr) * 32 + fk];
#pragma unroll
    for (int j = 0; j < 4; j++) bfv[j] = *(const short8*)&Bs[(wn + j * 16 + fr) * 32 + fk];
#pragma unroll
    for (int i = 0; i < 4; i++)
#pragma unroll
      for (int j = 0; j < 4; j++)
        acc[i][j] = __builtin_amdgcn_mfma_f32_16x16x32_bf16(af[i], bfv[j], acc[i][j], 0, 0, 0);
    __syncthreads();
  }

  const int crow = (lane >> 4) * 4;
  const int ccol = lane & 15;
#pragma unroll
  for (int j = 0; j < 4; j++) {
    const long col = bn + wn + j * 16 + ccol;
    const float bv = bias[col];
#pragma unroll
    for (int i = 0; i < 4; i++) {
#pragma unroll
      for (int r = 0; r < 4; r++) {
        const long row = bm + wm + i * 16 + crow + r;
        const float val = acc[i][j][r] + bv;
        if constexpr (__is_same(OutT, float)) C[row * ldc + col] = val;
        else                                  C[row * ldc + col] = f2bf(val);
      }
    }
  }
}

// ---------------- flash attention ----------------
// qkv: [4096][3072] bf16 (Q pre-scaled by 1/8 | K | V), out: [4096][1024] bf16
// grid: (16 qtiles, 16 heads, 2 batch); 4 waves, 32 q-rows each; KVBLK=64.

__global__ __launch_bounds__(256) void attn_fwd(
    const unsigned short* __restrict__ qkv, unsigned short* __restrict__ out) {
  __shared__ unsigned short Ks[64 * 72];   // [kv][d], pad 8 -> stride 144B
  __shared__ unsigned short Vs[64 * 72];   // [d][kv] (V^T)
  __shared__ unsigned short Ps[128 * 72];  // [q][kv]
  const int tid = threadIdx.x;
  const int lane = tid & 63;
  const int w = tid >> 6;
  const int qtile = blockIdx.x;
  const int h = blockIdx.y;
  const int b = blockIdx.z;
  const long rowbase = (long)b * 2048;
  const int hq = h * 64;
  const int fr = lane & 15;
  const int fg = lane >> 4;
  const int fk = fg * 8;

  // Q fragments held in registers for the whole kernel
  short8 qf[2][2];
#pragma unroll
  for (int mi = 0; mi < 2; mi++) {
    const long qr = rowbase + qtile * 128 + w * 32 + mi * 16 + fr;
#pragma unroll
    for (int kc = 0; kc < 2; kc++)
      qf[mi][kc] = *(const short8*)&qkv[qr * 3072 + hq + kc * 32 + fk];
  }

  f32x4 o[2][4] = {};
  float m_[2][4], s_[2][4];
#pragma unroll
  for (int mi = 0; mi < 2; mi++)
#pragma unroll
    for (int r = 0; r < 4; r++) { m_[mi][r] = -1e30f; s_[mi][r] = 0.f; }

  for (int t = 0; t < 32; t++) {
    __syncthreads();  // previous tile's LDS reads complete
    // stage K tile [64][64] and V^T tile
    for (int ch = tid; ch < 512; ch += 256) {
      const int row = ch >> 3, dc = (ch & 7) * 8;
      const long gr = rowbase + t * 64 + row;
      u16x8 kvv = *(const u16x8*)&qkv[gr * 3072 + 1024 + hq + dc];
      *(u16x8*)&Ks[row * 72 + dc] = kvv;
      u16x8 vvv = *(const u16x8*)&qkv[gr * 3072 + 2048 + hq + dc];
#pragma unroll
      for (int j = 0; j < 8; j++) Vs[(dc + j) * 72 + row] = vvv[j];
    }
    __syncthreads();

    short8 kf[4][2];
#pragma unroll
    for (int n = 0; n < 4; n++)
#pragma unroll
      for (int kc = 0; kc < 2; kc++)
        kf[n][kc] = *(const short8*)&Ks[(n * 16 + fr) * 72 + kc * 32 + fk];

#pragma unroll
    for (int mi = 0; mi < 2; mi++) {
      f32x4 sa[4];
#pragma unroll
      for (int n = 0; n < 4; n++) {
        f32x4 z = {0.f, 0.f, 0.f, 0.f};
        z = __builtin_amdgcn_mfma_f32_16x16x32_bf16(qf[mi][0], kf[n][0], z, 0, 0, 0);
        sa[n] = __builtin_amdgcn_mfma_f32_16x16x32_bf16(qf[mi][1], kf[n][1], z, 0, 0, 0);
      }
      // online softmax over kv (cols); lane holds rows fg*4+r, col n*16+fr
      float mx[4];
#pragma unroll
      for (int r = 0; r < 4; r++)
        mx[r] = fmaxf(fmaxf(sa[0][r], sa[1][r]), fmaxf(sa[2][r], sa[3][r]));
#pragma unroll
      for (int r = 0; r < 4; r++) {
        for (int off = 1; off < 16; off <<= 1) mx[r] = fmaxf(mx[r], __shfl_xor(mx[r], off));
      }
      float fac[4], nm[4], ps[4];
#pragma unroll
      for (int r = 0; r < 4; r++) {
        nm[r] = fmaxf(m_[mi][r], mx[r]);
        fac[r] = __expf(m_[mi][r] - nm[r]);
        m_[mi][r] = nm[r];
        ps[r] = 0.f;
      }
      unsigned short pb[4][4];
#pragma unroll
      for (int n = 0; n < 4; n++)
#pragma unroll
        for (int r = 0; r < 4; r++) {
          float p = __expf(sa[n][r] - nm[r]);
          ps[r] += p;
          pb[n][r] = f2bf(p);
        }
#pragma unroll
      for (int r = 0; r < 4; r++) {
        for (int off = 1; off < 16; off <<= 1) ps[r] += __shfl_xor(ps[r], off);
        s_[mi][r] = s_[mi][r] * fac[r] + ps[r];
      }
#pragma unroll
      for (int dj = 0; dj < 4; dj++)
#pragma unroll
        for (int r = 0; r < 4; r++) o[mi][dj][r] *= fac[r];
      // write P (wave-private rows)
#pragma unroll
      for (int n = 0; n < 4; n++)
#pragma unroll
        for (int r = 0; r < 4; r++)
          Ps[(w * 32 + mi * 16 + fg * 4 + r) * 72 + n * 16 + fr] = pb[n][r];
    }

    // PV: O += P @ V
    short8 pa[2][2], vf[4][2];
#pragma unroll
    for (int mi = 0; mi < 2; mi++)
#pragma unroll
      for (int kc = 0; kc < 2; kc++)
        pa[mi][kc] = *(const short8*)&Ps[(w * 32 + mi * 16 + fr) * 72 + kc * 32 + fk];
#pragma unroll
    for (int dj = 0; dj < 4; dj++)
#pragma unroll
      for (int kc = 0; kc < 2; kc++)
        vf[dj][kc] = *(const short8*)&Vs[(dj * 16 + fr) * 72 + kc * 32 + fk];
#pragma unroll
    for (int mi = 0; mi < 2; mi++)
#pragma unroll
      for (int dj = 0; dj < 4; dj++)
#pragma unroll
        for (int kc = 0; kc < 2; kc++)
          o[mi][dj] = __builtin_amdgcn_mfma_f32_16x16x32_bf16(pa[mi][kc], vf[dj][kc], o[mi][dj], 0, 0, 0);
  }

  // epilogue: divide by softmax sum, write bf16
#pragma unroll
  for (int mi = 0; mi < 2; mi++)
#pragma unroll
    for (int dj = 0; dj < 4; dj++)
#pragma unroll
      for (int r = 0; r < 4; r++) {
        const long row = rowbase + qtile * 128 + w * 32 + mi * 16 + fg * 4 + r;
        out[row * 1024 + hq + dj * 16 + fr] = f2bf(o[mi][dj][r] / s_[mi][r]);
      }
}

// ---------------- host ----------------

extern "C" void kernel_launch(void* const* d_in, const int* in_sizes, int n_in,
                              void* d_out, int out_size, void* d_ws, size_t ws_size,
                              hipStream_t stream) {
  const float* x  = (const float*)d_in[0];
  const float* wq = (const float*)d_in[1];
  const float* bq = (const float*)d_in[2];
  const float* wk = (const float*)d_in[3];
  const float* bk = (const float*)d_in[4];
  const float* wv = (const float*)d_in[5];
  const float* bv = (const float*)d_in[6];
  const float* wo = (const float*)d_in[7];
  const float* bo = (const float*)d_in[8];

  char* ws = (char*)d_ws;
  unsigned short* xb    = (unsigned short*)(ws);                       // 8 MB  [4096][1024]
  unsigned short* wqkvT = (unsigned short*)(ws + (8ull  << 20));       // 6 MB  [3072][1024]
  unsigned short* woT   = (unsigned short*)(ws + (14ull << 20));       // 2 MB  [1024][1024]
  float*          bqkv  = (float*)         (ws + (16ull << 20));       // 12 KB [3072]
  unsigned short* qkv   = (unsigned short*)(ws + (17ull << 20));       // 24 MB [4096][3072]
  unsigned short* attn  = (unsigned short*)(ws + (41ull << 20));       // 8 MB  [4096][1024]

  // x -> bf16 (4096*1024 = 4194304 elems, 4 per thread)
  cvt_bf16<<<4096, 256, 0, stream>>>((const float4*)x, (ushort4*)xb);
  // weights -> bf16 transposed; fold 1/8 score scale into wq/bq
  cvt_wT<<<dim3(32, 32), 256, 0, stream>>>(wq, wqkvT,                 0.125f);
  cvt_wT<<<dim3(32, 32), 256, 0, stream>>>(wk, wqkvT + 1024 * 1024,   1.0f);
  cvt_wT<<<dim3(32, 32), 256, 0, stream>>>(wv, wqkvT + 2 * 1024 * 1024, 1.0f);
  cvt_wT<<<dim3(32, 32), 256, 0, stream>>>(wo, woT,                   1.0f);
  pack_bias<<<12, 256, 0, stream>>>(bq, bk, bv, bqkv);

  // QKV projection: [4096,1024] @ [1024,3072] -> [4096,3072]
  gemm_bt<unsigned short><<<dim3(32, 24), 256, 0, stream>>>(xb, wqkvT, bqkv, qkv, 1024, 3072);

  // attention -> attn [4096][1024] (bf16)
  attn_fwd<<<dim3(16, 16, 2), 256, 0, stream>>>(qkv, attn);

  // output projection -> d_out (fp32)
  gemm_bt<float><<<dim3(32, 8), 256, 0, stream>>>(attn, woT, bo, (float*)d_out, 1024, 1024);
}

// Round 3
// 206.513 us; speedup vs baseline: 1.1713x; 1.1713x over previous
//
#include <hip/hip_runtime.h>

typedef __attribute__((ext_vector_type(8))) short short8;
typedef __attribute__((ext_vector_type(4))) short short4v;
typedef __attribute__((ext_vector_type(8))) unsigned short u16x8;
typedef __attribute__((ext_vector_type(4))) float f32x4;

__device__ inline unsigned short f2bf(float f) {
  union { float f; unsigned int u; } v; v.f = f;
  unsigned int r = v.u + 0x7FFFu + ((v.u >> 16) & 1u);
  return (unsigned short)(r >> 16);
}

__device__ inline void gload_lds16(const void* g, void* l) {
  __builtin_amdgcn_global_load_lds(
      (const __attribute__((address_space(1))) unsigned int*)g,
      (__attribute__((address_space(3))) unsigned int*)l, 16, 0, 0);
}

// ---------------- conversion kernels ----------------

__global__ void cvt_bf16(const float4* __restrict__ in, ushort4* __restrict__ out) {
  const int i = blockIdx.x * blockDim.x + threadIdx.x;
  float4 v = in[i];
  ushort4 o;
  o.x = f2bf(v.x); o.y = f2bf(v.y); o.z = f2bf(v.z); o.w = f2bf(v.w);
  out[i] = o;
}

__global__ __launch_bounds__(256) void cvt_wT(const float* __restrict__ w,
                                              unsigned short* __restrict__ wT,
                                              float scale) {
  __shared__ float t[32][33];
  const int k0 = blockIdx.x * 32;
  const int n0 = blockIdx.y * 32;
  const int tx = threadIdx.x & 31, ty = threadIdx.x >> 5;  // 32 x 8
#pragma unroll
  for (int i = 0; i < 32; i += 8)
    t[ty + i][tx] = w[(size_t)(k0 + ty + i) * 1024 + n0 + tx];
  __syncthreads();
#pragma unroll
  for (int i = 0; i < 32; i += 8)
    wT[(size_t)(n0 + ty + i) * 1024 + k0 + tx] = f2bf(t[tx][ty + i] * scale);
}

__global__ void pack_bias(const float* __restrict__ bq, const float* __restrict__ bk,
                          const float* __restrict__ bv, float* __restrict__ out) {
  const int i = blockIdx.x * 256 + threadIdx.x;  // 0..3071
  float v;
  if (i < 1024) v = bq[i] * 0.125f;
  else if (i < 2048) v = bk[i - 1024];
  else v = bv[i - 2048];
  out[i] = v;
}

// ---------------- GEMM (m97 structure, unchanged) ----------------

template <typename OutT>
__global__ __launch_bounds__(256) void gemm_bt(
    const unsigned short* __restrict__ A, const unsigned short* __restrict__ Bt,
    const float* __restrict__ bias, OutT* __restrict__ C,
    int K, int ldc) {
  __shared__ unsigned short As[128 * 32];
  __shared__ unsigned short Bs[128 * 32];
  const int tid = threadIdx.x;
  const int lane = tid & 63;
  const int wave = tid >> 6;
  const int wm = (wave >> 1) * 64;
  const int wn = (wave & 1) * 64;
  const long bm = (long)blockIdx.x * 128;
  const long bn = (long)blockIdx.y * 128;

  const int sr = tid >> 2;
  const int sc = (tid & 3) * 8;
  const unsigned short* Ag0 = A + (bm + sr) * (long)K + sc;
  const unsigned short* Ag1 = A + (bm + 64 + sr) * (long)K + sc;
  const unsigned short* Bg0 = Bt + (bn + sr) * (long)K + sc;
  const unsigned short* Bg1 = Bt + (bn + 64 + sr) * (long)K + sc;
  unsigned short* As0 = &As[tid * 8];
  unsigned short* As1 = &As[2048 + tid * 8];
  unsigned short* Bs0 = &Bs[tid * 8];
  unsigned short* Bs1 = &Bs[2048 + tid * 8];

  f32x4 acc[4][4] = {};

  const int fr = lane & 15;
  const int fk = (lane >> 4) * 8;

  for (int kt = 0; kt < K; kt += 32) {
    gload_lds16(Ag0, As0);
    gload_lds16(Ag1, As1);
    gload_lds16(Bg0, Bs0);
    gload_lds16(Bg1, Bs1);
    Ag0 += 32; Ag1 += 32; Bg0 += 32; Bg1 += 32;
    __syncthreads();
    short8 af[4], bfv[4];
#pragma unroll
    for (int i = 0; i < 4; i++) af[i] = *(const short8*)&As[(wm + i * 16 + fr) * 32 + fk];
#pragma unroll
    for (int j = 0; j < 4; j++) bfv[j] = *(const short8*)&Bs[(wn + j * 16 + fr) * 32 + fk];
#pragma unroll
    for (int i = 0; i < 4; i++)
#pragma unroll
      for (int j = 0; j < 4; j++)
        acc[i][j] = __builtin_amdgcn_mfma_f32_16x16x32_bf16(af[i], bfv[j], acc[i][j], 0, 0, 0);
    __syncthreads();
  }

  const int crow = (lane >> 4) * 4;
  const int ccol = lane & 15;
#pragma unroll
  for (int j = 0; j < 4; j++) {
    const long col = bn + wn + j * 16 + ccol;
    const float bv = bias[col];
#pragma unroll
    for (int i = 0; i < 4; i++) {
#pragma unroll
      for (int r = 0; r < 4; r++) {
        const long row = bm + wm + i * 16 + crow + r;
        const float val = acc[i][j][r] + bv;
        if constexpr (__is_same(OutT, float)) C[row * ldc + col] = val;
        else                                  C[row * ldc + col] = f2bf(val);
      }
    }
  }
}

// ---------------- flash attention (v2) ----------------
// QBLK=64 (4 waves x 16 q-rows), KVBLK=64. Grid: 1024 blocks, XCD-swizzled so
// blocks sharing (b,h) cluster on one XCD (KV tile set stays L2-resident).
// K: row-major [64][64] bf16, XOR-chunk swizzle (byte ^= (row&7)<<4), staged by
//    global_load_lds with pre-swizzled global source (LDS writes linear = conflict-free).
// V: [4][16]-subtiled layout for ds_read_b64_tr_b16 (HW transpose read):
//    u16 idx(kv,d) = (d&15) + (kv&3)*16 + ((kv>>3)&3)*64 + ((kv>>2)&1)*256 + (d>>4)*512 + (kv>>5)*2048
//    staged linear via global_load_lds with per-lane decoded source.
// P: LDS stride 68 (write banks fully spread, reads 8B-aligned).

#define TRRD(d, o) asm volatile("ds_read_b64_tr_b16 %0, %1 offset:" o \
                                : "=v"(d) : "v"(vtr) : "memory")

__global__ __launch_bounds__(256, 4) void attn_fwd(
    const unsigned short* __restrict__ qkv, unsigned short* __restrict__ out) {
  __shared__ unsigned short Ks[64 * 64];
  __shared__ unsigned short Vs[64 * 64];
  __shared__ unsigned short Ps[64 * 68];
  const int tid = threadIdx.x;
  const int lane = tid & 63;
  const int w = tid >> 6;

  // XCD-aware swizzle: xcd = blockIdx.x & 7 owns 4 (b,h) pairs x 32 qtiles
  const int xcd = blockIdx.x & 7, slot = blockIdx.x >> 3;  // slot 0..127
  const int pair = xcd * 4 + (slot >> 5);                  // 0..31
  const int qtile = slot & 31;
  const int h = pair & 15, b = pair >> 4;
  const long rowbase = (long)b * 2048;
  const int hq = h * 64;
  const int fr = lane & 15;
  const int fg = lane >> 4;
  const int fk = fg * 8;
  const int q0 = qtile * 64 + w * 16;

  // Q fragments in registers (A operand: row=fr, k=kc*32+fk+j), pre-scaled by 1/8
  short8 qf[2];
  {
    const long qr = rowbase + q0 + fr;
    qf[0] = *(const short8*)&qkv[qr * 3072 + hq + fk];
    qf[1] = *(const short8*)&qkv[qr * 3072 + hq + 32 + fk];
  }

  // K staging: chunk c = it*256+tid; LDS linear at c*16B; src row=c>>3, col-chunk=(tid&7)^(row&7)
  const int kr0 = tid >> 3, kr1 = 32 + (tid >> 3);
  const unsigned short* Kg0 = &qkv[(rowbase + kr0) * 3072 + 1024 + hq + (((tid & 7) ^ (kr0 & 7)) * 8)];
  const unsigned short* Kg1 = &qkv[(rowbase + kr1) * 3072 + 1024 + hq + (((tid & 7) ^ (kr1 & 7)) * 8)];
  // V staging: decode c -> (kv, d0):
  //   kv = ((c>>8)&1)*32 + ((c>>3)&3)*8 + ((c>>5)&1)*4 + ((c>>1)&3); d0 = ((c>>6)&3)*16 + (c&1)*8
  const int vkv0 = ((tid >> 3) & 3) * 8 + ((tid >> 5) & 1) * 4 + ((tid >> 1) & 3);
  const int vd0 = ((tid >> 6) & 3) * 16 + (tid & 1) * 8;
  const unsigned short* Vg0 = &qkv[(rowbase + vkv0) * 3072 + 2048 + hq + vd0];
  const unsigned short* Vg1 = &qkv[(rowbase + vkv0 + 32) * 3072 + 2048 + hq + vd0];
  unsigned short* KsD0 = &Ks[tid * 8];
  unsigned short* KsD1 = &Ks[2048 + tid * 8];
  unsigned short* VsD0 = &Vs[tid * 8];
  unsigned short* VsD1 = &Vs[2048 + tid * 8];

  const __attribute__((address_space(3))) unsigned short* vtr =
      (const __attribute__((address_space(3))) unsigned short*)&Vs[0] + lane * 4;

  f32x4 o[4] = {};
  float m_[4], s_[4];
#pragma unroll
  for (int r = 0; r < 4; r++) { m_[r] = -1e30f; s_[r] = 0.f; }

  for (int t = 0; t < 32; t++) {
    gload_lds16(Kg0, KsD0);
    gload_lds16(Kg1, KsD1);
    gload_lds16(Vg0, VsD0);
    gload_lds16(Vg1, VsD1);
    Kg0 += 64 * 3072; Kg1 += 64 * 3072; Vg0 += 64 * 3072; Vg1 += 64 * 3072;
    __syncthreads();  // drains vmcnt -> staged data visible

    // QK^T: S[q=fr-rows][kv] ; K B-fragment from swizzled Ks
    short8 kf[4][2];
#pragma unroll
    for (int n = 0; n < 4; n++) {
      const int row = n * 16 + fr;
#pragma unroll
      for (int kc = 0; kc < 2; kc++) {
        const int idx = (row * 64 + kc * 32 + fk) ^ ((row & 7) << 3);
        kf[n][kc] = *(const short8*)&Ks[idx];
      }
    }
    f32x4 sa[4];
#pragma unroll
    for (int n = 0; n < 4; n++) {
      f32x4 z = {0.f, 0.f, 0.f, 0.f};
      z = __builtin_amdgcn_mfma_f32_16x16x32_bf16(qf[0], kf[n][0], z, 0, 0, 0);
      sa[n] = __builtin_amdgcn_mfma_f32_16x16x32_bf16(qf[1], kf[n][1], z, 0, 0, 0);
    }

    // online softmax: lane holds rows fg*4+r, col n*16+fr
    float mx[4];
#pragma unroll
    for (int r = 0; r < 4; r++)
      mx[r] = fmaxf(fmaxf(sa[0][r], sa[1][r]), fmaxf(sa[2][r], sa[3][r]));
#pragma unroll
    for (int r = 0; r < 4; r++) {
      for (int off = 1; off < 16; off <<= 1) mx[r] = fmaxf(mx[r], __shfl_xor(mx[r], off));
    }
    float fac[4], nm[4], ps[4];
#pragma unroll
    for (int r = 0; r < 4; r++) {
      nm[r] = fmaxf(m_[r], mx[r]);
      fac[r] = __expf(m_[r] - nm[r]);
      m_[r] = nm[r];
      ps[r] = 0.f;
    }
    unsigned short pb[4][4];
#pragma unroll
    for (int n = 0; n < 4; n++)
#pragma unroll
      for (int r = 0; r < 4; r++) {
        float p = __expf(sa[n][r] - nm[r]);
        ps[r] += p;
        pb[n][r] = f2bf(p);
      }
#pragma unroll
    for (int r = 0; r < 4; r++) {
      for (int off = 1; off < 16; off <<= 1) ps[r] += __shfl_xor(ps[r], off);
      s_[r] = s_[r] * fac[r] + ps[r];
    }
#pragma unroll
    for (int dj = 0; dj < 4; dj++)
#pragma unroll
      for (int r = 0; r < 4; r++) o[dj][r] *= fac[r];
    // P -> LDS (wave-private rows w*16..w*16+15)
#pragma unroll
    for (int n = 0; n < 4; n++)
#pragma unroll
      for (int r = 0; r < 4; r++)
        Ps[(w * 16 + fg * 4 + r) * 68 + n * 16 + fr] = pb[n][r];

    // PV: A = P fragments (same-wave rows, no barrier needed)
    short8 pa[2];
#pragma unroll
    for (int kc = 0; kc < 2; kc++)
      pa[kc] = *(const short8*)&Ps[(w * 16 + fr) * 68 + kc * 32 + fk];

    // V^T B-fragments via HW transpose read; offsets = half*512 + dj*1024 + kc*4096 bytes
    short4v v0[4][2], v1[4][2];
    TRRD(v0[0][0], "0");    TRRD(v1[0][0], "512");
    TRRD(v0[1][0], "1024"); TRRD(v1[1][0], "1536");
    TRRD(v0[2][0], "2048"); TRRD(v1[2][0], "2560");
    TRRD(v0[3][0], "3072"); TRRD(v1[3][0], "3584");
    TRRD(v0[0][1], "4096"); TRRD(v1[0][1], "4608");
    TRRD(v0[1][1], "5120"); TRRD(v1[1][1], "5632");
    TRRD(v0[2][1], "6144"); TRRD(v1[2][1], "6656");
    TRRD(v0[3][1], "7168"); TRRD(v1[3][1], "7680");
    asm volatile("s_waitcnt lgkmcnt(0)" ::: "memory");
    __builtin_amdgcn_sched_barrier(0);

#pragma unroll
    for (int dj = 0; dj < 4; dj++) {
#pragma unroll
      for (int kc = 0; kc < 2; kc++) {
        short8 vf = __builtin_shufflevector(v0[dj][kc], v1[dj][kc], 0, 1, 2, 3, 4, 5, 6, 7);
        o[dj] = __builtin_amdgcn_mfma_f32_16x16x32_bf16(pa[kc], vf, o[dj], 0, 0, 0);
      }
    }
    __syncthreads();  // all reads done before next tile's staging
  }

#pragma unroll
  for (int dj = 0; dj < 4; dj++)
#pragma unroll
    for (int r = 0; r < 4; r++) {
      const long row = rowbase + q0 + fg * 4 + r;
      out[row * 1024 + hq + dj * 16 + fr] = f2bf(o[dj][r] / s_[r]);
    }
}

// ---------------- host ----------------

extern "C" void kernel_launch(void* const* d_in, const int* in_sizes, int n_in,
                              void* d_out, int out_size, void* d_ws, size_t ws_size,
                              hipStream_t stream) {
  const float* x  = (const float*)d_in[0];
  const float* wq = (const float*)d_in[1];
  const float* bq = (const float*)d_in[2];
  const float* wk = (const float*)d_in[3];
  const float* bk = (const float*)d_in[4];
  const float* wv = (const float*)d_in[5];
  const float* bv = (const float*)d_in[6];
  const float* wo = (const float*)d_in[7];
  const float* bo = (const float*)d_in[8];

  char* ws = (char*)d_ws;
  unsigned short* xb    = (unsigned short*)(ws);                       // 8 MB  [4096][1024]
  unsigned short* wqkvT = (unsigned short*)(ws + (8ull  << 20));       // 6 MB  [3072][1024]
  unsigned short* woT   = (unsigned short*)(ws + (14ull << 20));       // 2 MB  [1024][1024]
  float*          bqkv  = (float*)         (ws + (16ull << 20));       // 12 KB [3072]
  unsigned short* qkv   = (unsigned short*)(ws + (17ull << 20));       // 24 MB [4096][3072]
  unsigned short* attn  = (unsigned short*)(ws + (41ull << 20));       // 8 MB  [4096][1024]

  cvt_bf16<<<4096, 256, 0, stream>>>((const float4*)x, (ushort4*)xb);
  cvt_wT<<<dim3(32, 32), 256, 0, stream>>>(wq, wqkvT,                 0.125f);
  cvt_wT<<<dim3(32, 32), 256, 0, stream>>>(wk, wqkvT + 1024 * 1024,   1.0f);
  cvt_wT<<<dim3(32, 32), 256, 0, stream>>>(wv, wqkvT + 2 * 1024 * 1024, 1.0f);
  cvt_wT<<<dim3(32, 32), 256, 0, stream>>>(wo, woT,                   1.0f);
  pack_bias<<<12, 256, 0, stream>>>(bq, bk, bv, bqkv);

  gemm_bt<unsigned short><<<dim3(32, 24), 256, 0, stream>>>(xb, wqkvT, bqkv, qkv, 1024, 3072);

  attn_fwd<<<1024, 256, 0, stream>>>(qkv, attn);

  gemm_bt<float><<<dim3(32, 8), 256, 0, stream>>>(attn, woT, bo, (float*)d_out, 1024, 1024);
}